// Round 5
// baseline (264.748 us; speedup 1.0000x reference)
//
#include <hip/hip_runtime.h>
#include <hip/hip_bf16.h>

#define D 64
#define MARGIN 4e-5f

typedef __attribute__((ext_vector_type(8))) short bf16x8;
typedef __attribute__((ext_vector_type(4))) float f32x4;

// ---------------------------------------------------------------------------
// VectorQuantizer. Harness ref = numpy-f32 recompute; argmin must bit-match
// np-f32 (xx pairwise-8 sum, sequential-k FMA sgemm, first-min). Screen is a
// split-bf16 MFMA proxy: acc = dot - ee/2 (two 3-deep MFMA chains, each
// seeded C = -ee/4), argmax(acc) == argmin(dist), software-pipelined with the
// top-2 reduction of the previous tile. Rows with proxy gap < MARGIN go to
// the np-f32-exact fallback (coalesced via transposed eT[d][k]).
// d_out (float): quantized[N*D] | loss[1] | indices[N] | perplexity[1]
// ws: counts u32[K] | nunc+pad | loss f64 | nehq f32[K] | eenp f32[K]
//     | eh bf16[K*D] | el bf16[K*D] | eT f32[D*K] | list u32[]
// ---------------------------------------------------------------------------

__device__ __forceinline__ float np_pairwise_sumsq64(const float* a) {
    float r[8];
#pragma unroll
    for (int j = 0; j < 8; ++j) r[j] = __fmul_rn(a[j], a[j]);
#pragma unroll
    for (int i = 8; i < 64; i += 8)
#pragma unroll
        for (int j = 0; j < 8; ++j)
            r[j] = __fadd_rn(r[j], __fmul_rn(a[i + j], a[i + j]));
    return __fadd_rn(
        __fadd_rn(__fadd_rn(r[0], r[1]), __fadd_rn(r[2], r[3])),
        __fadd_rn(__fadd_rn(r[4], r[5]), __fadd_rn(r[6], r[7])));
}

__device__ __forceinline__ unsigned short f32_bf16_rne(float f) {
    unsigned u = __float_as_uint(f);
    return (unsigned short)((u + 0x7fffu + ((u >> 16) & 1u)) >> 16);
}

__global__ __launch_bounds__(256) void vq_prep(const float* __restrict__ emb, int K,
                                               float* __restrict__ eenp,
                                               float* __restrict__ nehq,
                                               unsigned short* __restrict__ eh,
                                               unsigned short* __restrict__ el,
                                               float* __restrict__ eT, int doT) {
    int k = blockIdx.x * blockDim.x + threadIdx.x;
    if (k >= K) return;
    const float* e = emb + (size_t)k * D;
    float s = np_pairwise_sumsq64(e);
    eenp[k] = s;
    nehq[k] = -0.25f * s;
#pragma unroll 8
    for (int d = 0; d < D; ++d) {
        float f = e[d];
        unsigned short hb = f32_bf16_rne(f);
        float hf = __uint_as_float(((unsigned)hb) << 16);
        eh[(size_t)k * D + d] = hb;
        el[(size_t)k * D + d] = f32_bf16_rne(f - hf);
        if (doT) eT[(size_t)d * K + k] = f;  // coalesced per d across threads
    }
}

// exact numpy-f32 argmin for one row (overflow path, ~never executed)
__device__ int np_exact_argmin(const float* xr, const float* __restrict__ emb,
                               const float* __restrict__ eenp, int K) {
    float xx = np_pairwise_sumsq64(xr);
    float bm = 1e30f;
    int bi = 0;
    for (int k = 0; k < K; ++k) {
        const float* e = emb + (size_t)k * D;
        float dot = 0.f;
#pragma unroll 8
        for (int d = 0; d < D; ++d) dot = __fmaf_rn(xr[d], e[d], dot);
        float dist = __fsub_rn(__fadd_rn(xx, eenp[k]), __fmul_rn(2.0f, dot));
        if (dist < bm) { bm = dist; bi = k; }
    }
    return bi;
}

#define CVT8(F0, F1, H, L)                                                    \
    do {                                                                      \
        float _f[8] = {F0.x, F0.y, F0.z, F0.w, F1.x, F1.y, F1.z, F1.w};       \
        _Pragma("unroll") for (int _i = 0; _i < 8; ++_i) {                    \
            unsigned _u = __float_as_uint(_f[_i]);                            \
            unsigned _hb = (_u + 0x7fffu + ((_u >> 16) & 1u)) >> 16;          \
            float _hf = __uint_as_float(_hb << 16);                           \
            float _r = _f[_i] - _hf;                                          \
            unsigned _u2 = __float_as_uint(_r);                               \
            unsigned _lb = (_u2 + 0x7fffu + ((_u2 >> 16) & 1u)) >> 16;        \
            H[_i] = (short)_hb;                                               \
            L[_i] = (short)_lb;                                               \
        }                                                                     \
    } while (0)

// load A-side frags for 16-code tile T: eh/el slices + (-ee/4) vec
#define LOADA(A0, A1, A2, A3, CB, T)                                          \
    do {                                                                      \
        const unsigned short* _pe = eh + (((size_t)((T) + sub)) << 6) + (grp << 3); \
        const unsigned short* _pl = el + (((size_t)((T) + sub)) << 6) + (grp << 3); \
        A0 = *(const bf16x8*)_pe;  A1 = *(const bf16x8*)(_pe + 32);           \
        A2 = *(const bf16x8*)_pl;  A3 = *(const bf16x8*)(_pl + 32);           \
        CB = *(const f32x4*)(nehq + (T) + (grp << 2));                        \
    } while (0)

// two 3-deep chains per row-tile, both seeded C = -ee/4 (no mov seeding)
#define MPHASE(AA, AB, F0, F1, F2, F3, CBH)                                   \
    do {                                                                      \
        _Pragma("unroll") for (int _rt = 0; _rt < 4; ++_rt)                   \
            AA[_rt] = __builtin_amdgcn_mfma_f32_16x16x32_bf16(F0, xh[_rt][0], CBH, 0, 0, 0); \
        _Pragma("unroll") for (int _rt = 0; _rt < 4; ++_rt)                   \
            AB[_rt] = __builtin_amdgcn_mfma_f32_16x16x32_bf16(F1, xh[_rt][1], CBH, 0, 0, 0); \
        _Pragma("unroll") for (int _rt = 0; _rt < 4; ++_rt)                   \
            AA[_rt] = __builtin_amdgcn_mfma_f32_16x16x32_bf16(F2, xh[_rt][0], AA[_rt], 0, 0, 0); \
        _Pragma("unroll") for (int _rt = 0; _rt < 4; ++_rt)                   \
            AB[_rt] = __builtin_amdgcn_mfma_f32_16x16x32_bf16(F3, xh[_rt][1], AB[_rt], 0, 0, 0); \
        _Pragma("unroll") for (int _rt = 0; _rt < 4; ++_rt)                   \
            AA[_rt] = __builtin_amdgcn_mfma_f32_16x16x32_bf16(F0, xl[_rt][0], AA[_rt], 0, 0, 0); \
        _Pragma("unroll") for (int _rt = 0; _rt < 4; ++_rt)                   \
            AB[_rt] = __builtin_amdgcn_mfma_f32_16x16x32_bf16(F1, xl[_rt][1], AB[_rt], 0, 0, 0); \
    } while (0)

// top-2 update from a value pair (codes C0, C0+1); old m1 used before update
#define PAIR(VA0, VB0, VA1, VB1, RT, C0)                                      \
    do {                                                                      \
        float _v0 = VA0 + VB0, _v1 = VA1 + VB1;                               \
        float _hi = fmaxf(_v0, _v1), _lo = fminf(_v0, _v1);                   \
        int _ih = (C0) + (_v0 < _v1 ? 1 : 0);                                 \
        bool _tk = _hi > m1[RT];                                              \
        m2[RT] = fmaxf(fmaxf(m2[RT], _lo), fminf(m1[RT], _hi));               \
        bi[RT] = _tk ? _ih : bi[RT];                                          \
        m1[RT] = fmaxf(m1[RT], _hi);                                          \
    } while (0)

#define REDUCE(AA, AB, TB)                                                    \
    do {                                                                      \
        _Pragma("unroll") for (int _rt = 0; _rt < 4; ++_rt) {                 \
            int _c0 = (TB) + g4;                                              \
            PAIR(AA[_rt][0], AB[_rt][0], AA[_rt][1], AB[_rt][1], _rt, _c0);   \
            PAIR(AA[_rt][2], AB[_rt][2], AA[_rt][3], AB[_rt][3], _rt, _c0 + 2); \
        }                                                                     \
    } while (0)

__global__ __launch_bounds__(256) void vq_screen(
    const float* __restrict__ x, const float* __restrict__ emb,
    const unsigned short* __restrict__ eh, const unsigned short* __restrict__ el,
    const float* __restrict__ nehq, const float* __restrict__ eenp,
    int N, int Kc,
    float* __restrict__ outq, float* __restrict__ outidx,
    unsigned* __restrict__ counts, double* __restrict__ loss,
    unsigned* __restrict__ nunc, unsigned* __restrict__ list, unsigned cap) {
    const int lane = threadIdx.x & 63;
    const int row0 = blockIdx.x * 256 + (threadIdx.x >> 6) * 64;  // 64 rows/wave
    const int sub = lane & 15, grp = lane >> 4;
    const int g4 = grp << 2;

    // persistent B frags: x rows, split bf16, 4 row-tiles x 2 k-slices
    bf16x8 xh[4][2], xl[4][2];
#pragma unroll
    for (int rt = 0; rt < 4; ++rt) {
        const float* xrow = x + (((size_t)(row0 + (rt << 4) + sub)) << 6) + (grp << 3);
#pragma unroll
        for (int s = 0; s < 2; ++s) {
            float4 f0 = *(const float4*)(xrow + (s << 5));
            float4 f1 = *(const float4*)(xrow + (s << 5) + 4);
            CVT8(f0, f1, xh[rt][s], xl[rt][s]);
        }
    }

    float m1[4], m2[4];
    int bi[4];
#pragma unroll
    for (int rt = 0; rt < 4; ++rt) { m1[rt] = -3e38f; m2[rt] = -3e38f; bi[rt] = 0; }

    bf16x8 p0, p1, p2, p3, q0, q1, q2, q3;
    f32x4 pc, qc;
    f32x4 aA[4], aB[4], bA[4], bB[4];

    LOADA(p0, p1, p2, p3, pc, 0);
    MPHASE(aA, aB, p0, p1, p2, p3, pc);  // tile 0
    LOADA(q0, q1, q2, q3, qc, 16);
#pragma unroll 1
    for (int tb = 0; tb < Kc; tb += 32) {
        int t2 = tb + 32 < Kc ? tb + 32 : 0;
        LOADA(p0, p1, p2, p3, pc, t2);
        MPHASE(bA, bB, q0, q1, q2, q3, qc);  // tile tb+16
        REDUCE(aA, aB, tb);                  // tile tb (prev results)
        int t3 = tb + 48 < Kc ? tb + 48 : 0;
        LOADA(q0, q1, q2, q3, qc, t3);
        MPHASE(aA, aB, p0, p1, p2, p3, pc);  // tile tb+32 (junk on last iter)
        REDUCE(bA, bB, tb + 16);             // tile tb+16
    }

    // merge the 4 code-groups (lanes sub, sub+16, sub+32, sub+48)
#pragma unroll
    for (int rt = 0; rt < 4; ++rt) {
#pragma unroll
        for (int off = 16; off <= 32; off <<= 1) {
            float om1 = __shfl_xor(m1[rt], off);
            float om2 = __shfl_xor(m2[rt], off);
            int obi = __shfl_xor(bi[rt], off);
            bool take = (om1 > m1[rt]) || (om1 == m1[rt] && obi < bi[rt]);
            m2[rt] = fmaxf(fminf(om1, m1[rt]), fmaxf(om2, m2[rt]));
            m1[rt] = take ? om1 : m1[rt];
            bi[rt] = take ? obi : bi[rt];
        }
    }

    // decide + scalar outputs (lanes 0-15 own rows sub + 16*rt)
    int dec[4];
#pragma unroll
    for (int rt = 0; rt < 4; ++rt) dec[rt] = bi[rt];
    if (lane < 16) {
#pragma unroll
        for (int rt = 0; rt < 4; ++rt) {
            int row = row0 + (rt << 4) + lane;
            bool amb = 2.0f * (m1[rt] - m2[rt]) < MARGIN;
            if (amb) {
                unsigned pos = atomicAdd(nunc, 1u);
                if (pos < cap) {
                    list[pos] = (unsigned)row;
                    dec[rt] = -1;
                } else {
                    dec[rt] = np_exact_argmin(x + (size_t)row * D, emb, eenp, Kc);
                }
            }
            if (dec[rt] >= 0) {
                outidx[row] = (float)dec[rt];
                atomicAdd(counts + dec[rt], 1u);
            }
        }
    }

    // quantized + loss: pass p covers rows 16p..16p+15; 4 lanes per row
    double lpart = 0.0;
#pragma unroll
    for (int p = 0; p < 4; ++p) {
        int dp = __shfl(dec[p], lane >> 2);
        if (dp >= 0) {
            int row = row0 + (p << 4) + (lane >> 2);
            int qo = (lane & 3) << 4;
            const float4* ep = (const float4*)(emb + (size_t)dp * D + qo);
            const float4* xp = (const float4*)(x + (size_t)row * D + qo);
            float4* qp = (float4*)(outq + (size_t)row * D + qo);
#pragma unroll
            for (int j = 0; j < 4; ++j) {
                float4 ev = ep[j], xv = xp[j];
                qp[j] = ev;
                double d0 = (double)ev.x - (double)xv.x;
                double d1 = (double)ev.y - (double)xv.y;
                double d2 = (double)ev.z - (double)xv.z;
                double d3 = (double)ev.w - (double)xv.w;
                lpart += d0 * d0 + d1 * d1 + d2 * d2 + d3 * d3;
            }
        }
    }
#pragma unroll
    for (int off = 32; off; off >>= 1) lpart += __shfl_down(lpart, off);
    if (lane == 0) atomicAdd(loss, lpart);
}

// wave-per-row exact np-f32 argmin; coalesced reads via eT[d][k]
__global__ __launch_bounds__(64) void vq_fallback(
    const float* __restrict__ x, const float* __restrict__ emb,
    const float* __restrict__ eT, const float* __restrict__ eenp, int N, int K,
    float* __restrict__ outq, float* __restrict__ outidx,
    unsigned* __restrict__ counts, double* __restrict__ loss,
    const unsigned* __restrict__ nunc, const unsigned* __restrict__ list,
    unsigned cap) {
    unsigned n = *nunc;
    if (n > cap) n = cap;
    int lane = threadIdx.x;
    const f32x4* eT4 = (const f32x4*)eT;  // [D][K/4]
    for (unsigned i = blockIdx.x; i < n; i += gridDim.x) {
        int r = (int)list[i];
        float xr[D];
        {
            const float4* xp = (const float4*)(x + (size_t)r * D);
#pragma unroll
            for (int j = 0; j < D / 4; ++j) {
                float4 v = xp[j];
                xr[4 * j + 0] = v.x; xr[4 * j + 1] = v.y;
                xr[4 * j + 2] = v.z; xr[4 * j + 3] = v.w;
            }
        }
        float xx = np_pairwise_sumsq64(xr);
        // lane owns codes k = kk*256 + lane*4 + j; 16 independent np-exact chains
        f32x4 dt[4];
#pragma unroll
        for (int kk = 0; kk < 4; ++kk) dt[kk] = (f32x4){0.f, 0.f, 0.f, 0.f};
#pragma unroll 8
        for (int d = 0; d < D; ++d) {
#pragma unroll
            for (int kk = 0; kk < 4; ++kk) {
                f32x4 ev = eT4[(size_t)d * 256 + kk * 64 + lane];
                dt[kk][0] = __fmaf_rn(xr[d], ev[0], dt[kk][0]);
                dt[kk][1] = __fmaf_rn(xr[d], ev[1], dt[kk][1]);
                dt[kk][2] = __fmaf_rn(xr[d], ev[2], dt[kk][2]);
                dt[kk][3] = __fmaf_rn(xr[d], ev[3], dt[kk][3]);
            }
        }
        float bm = 1e30f;
        int bi = 0;
#pragma unroll
        for (int kk = 0; kk < 4; ++kk)
#pragma unroll
            for (int j = 0; j < 4; ++j) {
                int k = kk * 256 + lane * 4 + j;  // ascending within lane
                float dist = __fsub_rn(__fadd_rn(xx, eenp[k]),
                                       __fmul_rn(2.0f, dt[kk][j]));
                if (dist < bm) { bm = dist; bi = k; }
            }
        // wave argmin, ties -> lowest index (numpy first-occurrence)
#pragma unroll
        for (int off = 1; off < 64; off <<= 1) {
            float ov = __shfl_xor(bm, off);
            int oi = __shfl_xor(bi, off);
            if (ov < bm || (ov == bm && oi < bi)) { bm = ov; bi = oi; }
        }
        float ev = emb[(size_t)bi * D + lane];
        float xv = xr[0];  // placeholder, real xv below
        xv = x[(size_t)r * D + lane];
        outq[(size_t)r * D + lane] = ev;
        double df = (double)ev - (double)xv;
        double lp = df * df;
#pragma unroll
        for (int off = 32; off; off >>= 1) lp += __shfl_down(lp, off);
        if (lane == 0) {
            outidx[r] = (float)bi;
            atomicAdd(counts + bi, 1u);
            atomicAdd(loss, lp);
        }
    }
}

__global__ __launch_bounds__(256) void vq_final(
    const unsigned* __restrict__ counts, const double* __restrict__ loss,
    int N, int K, float* __restrict__ out_loss, float* __restrict__ out_perp) {
    double part = 0.0;
    for (int k = threadIdx.x; k < K; k += 256) {
        double p = (double)counts[k] / (double)N;
        part += p * log(p + 1e-10);
    }
#pragma unroll
    for (int off = 32; off; off >>= 1) part += __shfl_down(part, off);
    __shared__ double ls[4];
    if ((threadIdx.x & 63) == 0) ls[threadIdx.x >> 6] = part;
    __syncthreads();
    if (threadIdx.x == 0) {
        double s = ls[0] + ls[1] + ls[2] + ls[3];
        *out_perp = (float)exp(-s);
        double diff2 = *loss / ((double)N * (double)D);
        *out_loss = (float)(1.25 * diff2);
    }
}

extern "C" void kernel_launch(void* const* d_in, const int* in_sizes, int n_in,
                              void* d_out, int out_size, void* d_ws, size_t ws_size,
                              hipStream_t stream) {
    const float* x = (const float*)d_in[0];
    const float* emb = (const float*)d_in[1];
    int N = in_sizes[0] / D;
    int K = in_sizes[1] / D;

    float* outq = (float*)d_out;
    float* out_loss = outq + (size_t)N * D;
    float* outidx = out_loss + 1;
    float* out_perp = outidx + N;

    char* ws = (char*)d_ws;
    unsigned* counts = (unsigned*)ws;                          // K*4
    unsigned* nunc = (unsigned*)(ws + (size_t)K * 4);          // 4 (+4 pad)
    double* loss = (double*)(ws + (size_t)K * 4 + 8);          // 8
    float* nehq = (float*)(ws + (size_t)K * 4 + 16);           // K*4
    float* eenp = (float*)(ws + (size_t)K * 8 + 16);           // K*4
    unsigned short* eh = (unsigned short*)(ws + (size_t)K * 12 + 16);  // K*D*2
    unsigned short* el = (unsigned short*)(ws + (size_t)K * 12 + 16 + (size_t)K * D * 2);
    float* eT = (float*)(ws + (size_t)K * 12 + 16 + (size_t)K * D * 4);  // D*K*4
    size_t head = (size_t)K * 12 + 16 + (size_t)K * D * 8;
    int doT = (ws_size >= head + 65536) ? 1 : 0;
    unsigned* list = (unsigned*)(ws + head);
    unsigned cap = 0;
    if (doT && ws_size > head + 4) cap = (unsigned)((ws_size - head) / 4);
    if (cap > (unsigned)N) cap = (unsigned)N;

    hipMemsetAsync(d_ws, 0, (size_t)K * 4 + 16, stream);  // counts+nunc+loss

    vq_prep<<<(K + 255) / 256, 256, 0, stream>>>(emb, K, eenp, nehq, eh, el, eT, doT);
    vq_screen<<<N / 256, 256, 0, stream>>>(x, emb, eh, el, nehq, eenp, N, K,
                                           outq, outidx, counts, loss,
                                           nunc, list, cap);
    vq_fallback<<<2048, 64, 0, stream>>>(x, emb, eT, eenp, N, K, outq, outidx,
                                         counts, loss, nunc, list, cap);
    vq_final<<<1, 256, 0, stream>>>(counts, loss, N, K, out_loss, out_perp);
}

// Round 6
// 252.362 us; speedup vs baseline: 1.0491x; 1.0491x over previous
//
#include <hip/hip_runtime.h>
#include <hip/hip_bf16.h>

#define D 64
#define MARGIN 4e-5f

typedef __attribute__((ext_vector_type(8))) short bf16x8;
typedef __attribute__((ext_vector_type(4))) float f32x4;

// ---------------------------------------------------------------------------
// VectorQuantizer. Harness ref = numpy-f32 recompute; argmin must bit-match
// np-f32 (xx pairwise-8 sum, sequential-k FMA sgemm, first-min). Screen is a
// split-bf16 MFMA proxy: acc = dot - ee/2 (6-MFMA chain seeded C = -ee/2),
// argmax(acc) == argmin(dist). 32 rows/wave (rt=2) -> 4096 waves for TLP.
// Rows with proxy gap < MARGIN go to the np-f32-exact fallback (eT-coalesced).
// d_out (float): quantized[N*D] | loss[1] | indices[N] | perplexity[1]
// ws: counts u32[K] | nunc+pad | loss f64 | neh f32[K] | eenp f32[K]
//     | eh bf16[K*D] | el bf16[K*D] | eT f32[D*K] | list u32[]
// ---------------------------------------------------------------------------

__device__ __forceinline__ float np_pairwise_sumsq64(const float* a) {
    float r[8];
#pragma unroll
    for (int j = 0; j < 8; ++j) r[j] = __fmul_rn(a[j], a[j]);
#pragma unroll
    for (int i = 8; i < 64; i += 8)
#pragma unroll
        for (int j = 0; j < 8; ++j)
            r[j] = __fadd_rn(r[j], __fmul_rn(a[i + j], a[i + j]));
    return __fadd_rn(
        __fadd_rn(__fadd_rn(r[0], r[1]), __fadd_rn(r[2], r[3])),
        __fadd_rn(__fadd_rn(r[4], r[5]), __fadd_rn(r[6], r[7])));
}

#define CVT8(F0, F1, H, L)                                                    \
    do {                                                                      \
        float _f[8] = {F0.x, F0.y, F0.z, F0.w, F1.x, F1.y, F1.z, F1.w};       \
        _Pragma("unroll") for (int _i = 0; _i < 8; ++_i) {                    \
            unsigned _u = __float_as_uint(_f[_i]);                            \
            unsigned _hb = (_u + 0x7fffu + ((_u >> 16) & 1u)) >> 16;          \
            float _hf = __uint_as_float(_hb << 16);                           \
            float _r = _f[_i] - _hf;                                          \
            unsigned _u2 = __float_as_uint(_r);                               \
            unsigned _lb = (_u2 + 0x7fffu + ((_u2 >> 16) & 1u)) >> 16;        \
            H[_i] = (short)_hb;                                               \
            L[_i] = (short)_lb;                                               \
        }                                                                     \
    } while (0)

// one fused prep: blocks [0,32) eh/el convert; [32,36) sumsq; [36,292) eT
__global__ __launch_bounds__(256) void vq_prep_all(
    const float* __restrict__ emb, int K,
    float* __restrict__ eenp, float* __restrict__ neh,
    unsigned short* __restrict__ eh, unsigned short* __restrict__ el,
    float* __restrict__ eT) {
    int b = blockIdx.x;
    if (b < 32) {
        int t = b * 256 + threadIdx.x;          // 8192 threads x 8 elems
        int k = t >> 3, c = (t & 7) << 3;
        const float* e = emb + (size_t)k * D + c;
        float4 f0 = *(const float4*)e;
        float4 f1 = *(const float4*)(e + 4);
        bf16x8 h, l;
        CVT8(f0, f1, h, l);
        *(bf16x8*)(eh + (size_t)k * D + c) = h;
        *(bf16x8*)(el + (size_t)k * D + c) = l;
    } else if (b < 36) {
        int k = (b - 32) * 256 + threadIdx.x;   // 1024 codes
        float s = np_pairwise_sumsq64(emb + (size_t)k * D);
        eenp[k] = s;
        neh[k] = -0.5f * s;
    } else {
        int t = (b - 36) * 256 + threadIdx.x;   // 65536 = D*K, coalesced write
        int d = t / K, k = t - d * K;
        eT[t] = emb[(size_t)k * D + d];
    }
}

// exact numpy-f32 argmin for one row (overflow path, ~never executed)
__device__ int np_exact_argmin(const float* xr, const float* __restrict__ emb,
                               const float* __restrict__ eenp, int K) {
    float xx = np_pairwise_sumsq64(xr);
    float bm = 1e30f;
    int bi = 0;
    for (int k = 0; k < K; ++k) {
        const float* e = emb + (size_t)k * D;
        float dot = 0.f;
#pragma unroll 8
        for (int d = 0; d < D; ++d) dot = __fmaf_rn(xr[d], e[d], dot);
        float dist = __fsub_rn(__fadd_rn(xx, eenp[k]), __fmul_rn(2.0f, dot));
        if (dist < bm) { bm = dist; bi = k; }
    }
    return bi;
}

// load A-side frags for 16-code tile T: eh/el slices + (-ee/2) vec
#define LOADA(A0, A1, A2, A3, CB, T)                                          \
    do {                                                                      \
        const unsigned short* _pe = eh + (((size_t)((T) + sub)) << 6) + (grp << 3); \
        const unsigned short* _pl = el + (((size_t)((T) + sub)) << 6) + (grp << 3); \
        A0 = *(const bf16x8*)_pe;  A1 = *(const bf16x8*)(_pe + 32);           \
        A2 = *(const bf16x8*)_pl;  A3 = *(const bf16x8*)(_pl + 32);           \
        CB = *(const f32x4*)(neh + (T) + (grp << 2));                         \
    } while (0)

// top-2 update from value pair (codes C0, C0+1); ties -> np first-min
#define PAIR2(V0, V1, RT, C0)                                                 \
    do {                                                                      \
        float _hi = fmaxf(V0, V1), _lo = fminf(V0, V1);                       \
        int _ih = (C0) + ((V0) < (V1) ? 1 : 0);                               \
        bool _tk = _hi > m1[RT];                                              \
        m2[RT] = fmaxf(fmaxf(m2[RT], _lo), fminf(m1[RT], _hi));               \
        bi[RT] = _tk ? _ih : bi[RT];                                          \
        m1[RT] = fmaxf(m1[RT], _hi);                                          \
    } while (0)

__global__ __launch_bounds__(256) void vq_screen(
    const float* __restrict__ x, const float* __restrict__ emb,
    const unsigned short* __restrict__ eh, const unsigned short* __restrict__ el,
    const float* __restrict__ neh, const float* __restrict__ eenp,
    int N, int Kc,
    float* __restrict__ outq, float* __restrict__ outidx,
    unsigned* __restrict__ counts, double* __restrict__ loss,
    unsigned* __restrict__ nunc, unsigned* __restrict__ list, unsigned cap) {
    const int lane = threadIdx.x & 63;
    const int row0 = blockIdx.x * 128 + (threadIdx.x >> 6) * 32;  // 32 rows/wave
    const int sub = lane & 15, grp = lane >> 4;
    const int g4 = grp << 2;

    // persistent B frags: x rows, split bf16, 2 row-tiles x 2 k-slices
    bf16x8 xh[2][2], xl[2][2];
#pragma unroll
    for (int rt = 0; rt < 2; ++rt) {
        const float* xrow = x + (((size_t)(row0 + (rt << 4) + sub)) << 6) + (grp << 3);
#pragma unroll
        for (int s = 0; s < 2; ++s) {
            float4 f0 = *(const float4*)(xrow + (s << 5));
            float4 f1 = *(const float4*)(xrow + (s << 5) + 4);
            CVT8(f0, f1, xh[rt][s], xl[rt][s]);
        }
    }

    float m1[2] = {-3e38f, -3e38f}, m2[2] = {-3e38f, -3e38f};
    int bi[2] = {0, 0};

    bf16x8 a0, a1, a2, a3;  // eh slice0/1, el slice0/1
    f32x4 cb;
    LOADA(a0, a1, a2, a3, cb, 0);
    for (int tb = 0; tb < Kc; tb += 16) {
        bf16x8 n0, n1, n2, n3;
        f32x4 nb;
        int tn = tb + 16 < Kc ? tb + 16 : 0;
        LOADA(n0, n1, n2, n3, nb, tn);

        f32x4 acc[2];
#pragma unroll
        for (int rt = 0; rt < 2; ++rt)
            acc[rt] = __builtin_amdgcn_mfma_f32_16x16x32_bf16(a0, xh[rt][0], cb, 0, 0, 0);
#pragma unroll
        for (int rt = 0; rt < 2; ++rt)
            acc[rt] = __builtin_amdgcn_mfma_f32_16x16x32_bf16(a2, xh[rt][0], acc[rt], 0, 0, 0);
#pragma unroll
        for (int rt = 0; rt < 2; ++rt)
            acc[rt] = __builtin_amdgcn_mfma_f32_16x16x32_bf16(a0, xl[rt][0], acc[rt], 0, 0, 0);
#pragma unroll
        for (int rt = 0; rt < 2; ++rt)
            acc[rt] = __builtin_amdgcn_mfma_f32_16x16x32_bf16(a1, xh[rt][1], acc[rt], 0, 0, 0);
#pragma unroll
        for (int rt = 0; rt < 2; ++rt)
            acc[rt] = __builtin_amdgcn_mfma_f32_16x16x32_bf16(a3, xh[rt][1], acc[rt], 0, 0, 0);
#pragma unroll
        for (int rt = 0; rt < 2; ++rt)
            acc[rt] = __builtin_amdgcn_mfma_f32_16x16x32_bf16(a1, xl[rt][1], acc[rt], 0, 0, 0);

        // top-2 update; per-lane codes ascend -> np first-min
#pragma unroll
        for (int rt = 0; rt < 2; ++rt) {
            int c0 = tb + g4;
            PAIR2(acc[rt][0], acc[rt][1], rt, c0);
            PAIR2(acc[rt][2], acc[rt][3], rt, c0 + 2);
        }
        a0 = n0; a1 = n1; a2 = n2; a3 = n3; cb = nb;
    }

    // merge the 4 code-groups (lanes sub, sub+16, sub+32, sub+48)
#pragma unroll
    for (int rt = 0; rt < 2; ++rt) {
#pragma unroll
        for (int off = 16; off <= 32; off <<= 1) {
            float om1 = __shfl_xor(m1[rt], off);
            float om2 = __shfl_xor(m2[rt], off);
            int obi = __shfl_xor(bi[rt], off);
            bool take = (om1 > m1[rt]) || (om1 == m1[rt] && obi < bi[rt]);
            m2[rt] = fmaxf(fminf(om1, m1[rt]), fmaxf(om2, m2[rt]));
            m1[rt] = take ? om1 : m1[rt];
            bi[rt] = take ? obi : bi[rt];
        }
    }

    // decide + scalar outputs (lanes 0-15 own rows sub + 16*rt)
    int dec[2];
#pragma unroll
    for (int rt = 0; rt < 2; ++rt) dec[rt] = bi[rt];
    if (lane < 16) {
#pragma unroll
        for (int rt = 0; rt < 2; ++rt) {
            int row = row0 + (rt << 4) + lane;
            bool amb = 2.0f * (m1[rt] - m2[rt]) < MARGIN;
            if (amb) {
                unsigned pos = atomicAdd(nunc, 1u);
                if (pos < cap) {
                    list[pos] = (unsigned)row;
                    dec[rt] = -1;
                } else {
                    dec[rt] = np_exact_argmin(x + (size_t)row * D, emb, eenp, Kc);
                }
            }
            if (dec[rt] >= 0) {
                outidx[row] = (float)dec[rt];
                atomicAdd(counts + dec[rt], 1u);
            }
        }
    }

    // quantized + loss: pass p covers rows 16p..16p+15; 4 lanes per row
    double lpart = 0.0;
#pragma unroll
    for (int p = 0; p < 2; ++p) {
        int dp = __shfl(dec[p], lane >> 2);
        if (dp >= 0) {
            int row = row0 + (p << 4) + (lane >> 2);
            int qo = (lane & 3) << 4;
            const float4* ep = (const float4*)(emb + (size_t)dp * D + qo);
            const float4* xp = (const float4*)(x + (size_t)row * D + qo);
            float4* qp = (float4*)(outq + (size_t)row * D + qo);
#pragma unroll
            for (int j = 0; j < 4; ++j) {
                float4 ev = ep[j], xv = xp[j];
                qp[j] = ev;
                double d0 = (double)ev.x - (double)xv.x;
                double d1 = (double)ev.y - (double)xv.y;
                double d2 = (double)ev.z - (double)xv.z;
                double d3 = (double)ev.w - (double)xv.w;
                lpart += d0 * d0 + d1 * d1 + d2 * d2 + d3 * d3;
            }
        }
    }
#pragma unroll
    for (int off = 32; off; off >>= 1) lpart += __shfl_down(lpart, off);
    if (lane == 0) atomicAdd(loss, lpart);
}

// wave-per-row exact np-f32 argmin; coalesced reads via eT[d][k]
__global__ __launch_bounds__(64) void vq_fallback(
    const float* __restrict__ x, const float* __restrict__ emb,
    const float* __restrict__ eT, const float* __restrict__ eenp, int N, int K,
    float* __restrict__ outq, float* __restrict__ outidx,
    unsigned* __restrict__ counts, double* __restrict__ loss,
    const unsigned* __restrict__ nunc, const unsigned* __restrict__ list,
    unsigned cap) {
    unsigned n = *nunc;
    if (n > cap) n = cap;
    int lane = threadIdx.x;
    const f32x4* eT4 = (const f32x4*)eT;  // [D][K/4]
    for (unsigned i = blockIdx.x; i < n; i += gridDim.x) {
        int r = (int)list[i];
        float xr[D];
        {
            const float4* xp = (const float4*)(x + (size_t)r * D);
#pragma unroll
            for (int j = 0; j < D / 4; ++j) {
                float4 v = xp[j];
                xr[4 * j + 0] = v.x; xr[4 * j + 1] = v.y;
                xr[4 * j + 2] = v.z; xr[4 * j + 3] = v.w;
            }
        }
        float xx = np_pairwise_sumsq64(xr);
        // lane owns codes k = kk*256 + lane*4 + j; np-exact sequential-k chains
        f32x4 dt[4];
#pragma unroll
        for (int kk = 0; kk < 4; ++kk) dt[kk] = (f32x4){0.f, 0.f, 0.f, 0.f};
#pragma unroll 8
        for (int d = 0; d < D; ++d) {
#pragma unroll
            for (int kk = 0; kk < 4; ++kk) {
                f32x4 ev = eT4[(size_t)d * 256 + kk * 64 + lane];
                dt[kk][0] = __fmaf_rn(xr[d], ev[0], dt[kk][0]);
                dt[kk][1] = __fmaf_rn(xr[d], ev[1], dt[kk][1]);
                dt[kk][2] = __fmaf_rn(xr[d], ev[2], dt[kk][2]);
                dt[kk][3] = __fmaf_rn(xr[d], ev[3], dt[kk][3]);
            }
        }
        float bm = 1e30f;
        int bi = 0;
#pragma unroll
        for (int kk = 0; kk < 4; ++kk)
#pragma unroll
            for (int j = 0; j < 4; ++j) {
                int k = kk * 256 + lane * 4 + j;  // ascending within lane
                float dist = __fsub_rn(__fadd_rn(xx, eenp[k]),
                                       __fmul_rn(2.0f, dt[kk][j]));
                if (dist < bm) { bm = dist; bi = k; }
            }
        // wave argmin, ties -> lowest index (numpy first-occurrence)
#pragma unroll
        for (int off = 1; off < 64; off <<= 1) {
            float ov = __shfl_xor(bm, off);
            int oi = __shfl_xor(bi, off);
            if (ov < bm || (ov == bm && oi < bi)) { bm = ov; bi = oi; }
        }
        float ev = emb[(size_t)bi * D + lane];
        float xv = x[(size_t)r * D + lane];
        outq[(size_t)r * D + lane] = ev;
        double df = (double)ev - (double)xv;
        double lp = df * df;
#pragma unroll
        for (int off = 32; off; off >>= 1) lp += __shfl_down(lp, off);
        if (lane == 0) {
            outidx[r] = (float)bi;
            atomicAdd(counts + bi, 1u);
            atomicAdd(loss, lp);
        }
    }
}

__global__ __launch_bounds__(256) void vq_final(
    const unsigned* __restrict__ counts, const double* __restrict__ loss,
    int N, int K, float* __restrict__ out_loss, float* __restrict__ out_perp) {
    double part = 0.0;
    for (int k = threadIdx.x; k < K; k += 256) {
        double p = (double)counts[k] / (double)N;
        part += p * log(p + 1e-10);
    }
#pragma unroll
    for (int off = 32; off; off >>= 1) part += __shfl_down(part, off);
    __shared__ double ls[4];
    if ((threadIdx.x & 63) == 0) ls[threadIdx.x >> 6] = part;
    __syncthreads();
    if (threadIdx.x == 0) {
        double s = ls[0] + ls[1] + ls[2] + ls[3];
        *out_perp = (float)exp(-s);
        double diff2 = *loss / ((double)N * (double)D);
        *out_loss = (float)(1.25 * diff2);
    }
}

extern "C" void kernel_launch(void* const* d_in, const int* in_sizes, int n_in,
                              void* d_out, int out_size, void* d_ws, size_t ws_size,
                              hipStream_t stream) {
    const float* x = (const float*)d_in[0];
    const float* emb = (const float*)d_in[1];
    int N = in_sizes[0] / D;
    int K = in_sizes[1] / D;

    float* outq = (float*)d_out;
    float* out_loss = outq + (size_t)N * D;
    float* outidx = out_loss + 1;
    float* out_perp = outidx + N;

    char* ws = (char*)d_ws;
    unsigned* counts = (unsigned*)ws;                          // K*4
    unsigned* nunc = (unsigned*)(ws + (size_t)K * 4);          // 4 (+4 pad)
    double* loss = (double*)(ws + (size_t)K * 4 + 8);          // 8
    float* neh = (float*)(ws + (size_t)K * 4 + 16);            // K*4
    float* eenp = (float*)(ws + (size_t)K * 8 + 16);           // K*4
    unsigned short* eh = (unsigned short*)(ws + (size_t)K * 12 + 16);  // K*D*2
    unsigned short* el = (unsigned short*)(ws + (size_t)K * 12 + 16 + (size_t)K * D * 2);
    float* eT = (float*)(ws + (size_t)K * 12 + 16 + (size_t)K * D * 4);  // D*K*4
    size_t head = (size_t)K * 12 + 16 + (size_t)K * D * 8;
    int doT = (ws_size >= head + 65536) ? 1 : 0;
    unsigned* list = (unsigned*)(ws + head);
    unsigned cap = 0;
    if (doT && ws_size > head + 4) cap = (unsigned)((ws_size - head) / 4);
    if (cap > (unsigned)N) cap = (unsigned)N;

    hipMemsetAsync(d_ws, 0, (size_t)K * 4 + 16, stream);  // counts+nunc+loss

    // prep: 32 blocks eh/el (K*D/8/256), 4 blocks sums, K*D/256 blocks eT
    int nb_ehel = (K * D / 8 + 255) / 256;
    int nb_sum = (K + 255) / 256;
    int nb_eT = (K * D + 255) / 256;
    vq_prep_all<<<nb_ehel + nb_sum + nb_eT, 256, 0, stream>>>(
        emb, K, eenp, neh, eh, el, eT);
    vq_screen<<<N / 128, 256, 0, stream>>>(x, emb, eh, el, neh, eenp, N, K,
                                           outq, outidx, counts, loss,
                                           nunc, list, cap);
    vq_fallback<<<1024, 64, 0, stream>>>(x, emb, eT, eenp, N, K, outq, outidx,
                                         counts, loss, nunc, list, cap);
    vq_final<<<1, 256, 0, stream>>>(counts, loss, N, K, out_loss, out_perp);
}

// Round 7
// 193.961 us; speedup vs baseline: 1.3650x; 1.3011x over previous
//
#include <hip/hip_runtime.h>
#include <hip/hip_bf16.h>

#define D 64
#define MARGIN 4e-5f
#define KS 2          // k-split factor across blocks

typedef __attribute__((ext_vector_type(8))) short bf16x8;
typedef __attribute__((ext_vector_type(4))) float f32x4;

// ---------------------------------------------------------------------------
// VectorQuantizer. Harness ref = numpy-f32 recompute; argmin must bit-match
// np-f32 (xx pairwise-8 sum, sequential-k FMA sgemm, first-min). Screen is a
// split-bf16 MFMA proxy: acc = dot - ee/2 (6-MFMA chain seeded C = -ee/2),
// argmax(acc) == argmin(dist). Geometry: block = 4 waves x 64 rows (rt=4),
// each block scans K/KS codes (k-split) -> 2x blocks, same per-wave traffic.
// Screen emits per-slice (m1,m2,bi) triples into outq[row][kslice*3..+2]
// (scratch); vq_merge combines slices (ascending order => np first-min),
// applies MARGIN, writes idx/counts/quantized/loss. Ambiguous rows go to the
// np-f32-exact fallback (eT-coalesced, 4 rows batched per wave pass).
// d_out (float): quantized[N*D] | loss[1] | indices[N] | perplexity[1]
// ws: counts u32[K] | nunc+pad | loss f64 | neh f32[K] | eenp f32[K]
//     | eh bf16[K*D] | el bf16[K*D] | eT f32[D*K] | list u32[]
// ---------------------------------------------------------------------------

__device__ __forceinline__ float np_pairwise_sumsq64(const float* a) {
    float r[8];
#pragma unroll
    for (int j = 0; j < 8; ++j) r[j] = __fmul_rn(a[j], a[j]);
#pragma unroll
    for (int i = 8; i < 64; i += 8)
#pragma unroll
        for (int j = 0; j < 8; ++j)
            r[j] = __fadd_rn(r[j], __fmul_rn(a[i + j], a[i + j]));
    return __fadd_rn(
        __fadd_rn(__fadd_rn(r[0], r[1]), __fadd_rn(r[2], r[3])),
        __fadd_rn(__fadd_rn(r[4], r[5]), __fadd_rn(r[6], r[7])));
}

#define CVT8(F0, F1, H, L)                                                    \
    do {                                                                      \
        float _f[8] = {F0.x, F0.y, F0.z, F0.w, F1.x, F1.y, F1.z, F1.w};       \
        _Pragma("unroll") for (int _i = 0; _i < 8; ++_i) {                    \
            unsigned _u = __float_as_uint(_f[_i]);                            \
            unsigned _hb = (_u + 0x7fffu + ((_u >> 16) & 1u)) >> 16;          \
            float _hf = __uint_as_float(_hb << 16);                           \
            float _r = _f[_i] - _hf;                                          \
            unsigned _u2 = __float_as_uint(_r);                               \
            unsigned _lb = (_u2 + 0x7fffu + ((_u2 >> 16) & 1u)) >> 16;        \
            H[_i] = (short)_hb;                                               \
            L[_i] = (short)_lb;                                               \
        }                                                                     \
    } while (0)

// one fused prep: blocks [0,32) eh/el convert; [32,36) sumsq; [36,292) eT
__global__ __launch_bounds__(256) void vq_prep_all(
    const float* __restrict__ emb, int K,
    float* __restrict__ eenp, float* __restrict__ neh,
    unsigned short* __restrict__ eh, unsigned short* __restrict__ el,
    float* __restrict__ eT) {
    int b = blockIdx.x;
    if (b < 32) {
        int t = b * 256 + threadIdx.x;          // 8192 threads x 8 elems
        int k = t >> 3, c = (t & 7) << 3;
        const float* e = emb + (size_t)k * D + c;
        float4 f0 = *(const float4*)e;
        float4 f1 = *(const float4*)(e + 4);
        bf16x8 h, l;
        CVT8(f0, f1, h, l);
        *(bf16x8*)(eh + (size_t)k * D + c) = h;
        *(bf16x8*)(el + (size_t)k * D + c) = l;
    } else if (b < 36) {
        int k = (b - 32) * 256 + threadIdx.x;   // 1024 codes
        float s = np_pairwise_sumsq64(emb + (size_t)k * D);
        eenp[k] = s;
        neh[k] = -0.5f * s;
    } else {
        int t = (b - 36) * 256 + threadIdx.x;   // 65536 = D*K, coalesced write
        int d = t / K, k = t - d * K;
        eT[t] = emb[(size_t)k * D + d];
    }
}

// exact numpy-f32 argmin for one row (overflow path, ~never executed)
__device__ int np_exact_argmin(const float* xr, const float* __restrict__ emb,
                               const float* __restrict__ eenp, int K) {
    float xx = np_pairwise_sumsq64(xr);
    float bm = 1e30f;
    int bi = 0;
    for (int k = 0; k < K; ++k) {
        const float* e = emb + (size_t)k * D;
        float dot = 0.f;
#pragma unroll 8
        for (int d = 0; d < D; ++d) dot = __fmaf_rn(xr[d], e[d], dot);
        float dist = __fsub_rn(__fadd_rn(xx, eenp[k]), __fmul_rn(2.0f, dot));
        if (dist < bm) { bm = dist; bi = k; }
    }
    return bi;
}

// load A-side frags for 16-code tile T: eh/el slices + (-ee/2) vec
#define LOADA(A0, A1, A2, A3, CB, T)                                          \
    do {                                                                      \
        const unsigned short* _pe = eh + (((size_t)((T) + sub)) << 6) + (grp << 3); \
        const unsigned short* _pl = el + (((size_t)((T) + sub)) << 6) + (grp << 3); \
        A0 = *(const bf16x8*)_pe;  A1 = *(const bf16x8*)(_pe + 32);           \
        A2 = *(const bf16x8*)_pl;  A3 = *(const bf16x8*)(_pl + 32);           \
        CB = *(const f32x4*)(neh + (T) + (grp << 2));                         \
    } while (0)

__global__ __launch_bounds__(256) void vq_screen(
    const float* __restrict__ x,
    const unsigned short* __restrict__ eh, const unsigned short* __restrict__ el,
    const float* __restrict__ neh, int N, int K,
    float* __restrict__ outq /* triples scratch */) {
    const int lane = threadIdx.x & 63;
    const int kslice = blockIdx.x & (KS - 1);
    const int rowblk = blockIdx.x >> 1;  // KS == 2
    const int row0 = rowblk * 256 + (threadIdx.x >> 6) * 64;  // 64 rows/wave
    const int sub = lane & 15, grp = lane >> 4;
    const int g4 = grp << 2;
    const int k0 = kslice * (K >> 1), kend = k0 + (K >> 1);

    // persistent B frags: x rows, split bf16, 4 row-tiles x 2 k-slices
    bf16x8 xh[4][2], xl[4][2];
#pragma unroll
    for (int rt = 0; rt < 4; ++rt) {
        const float* xrow = x + (((size_t)(row0 + (rt << 4) + sub)) << 6) + (grp << 3);
#pragma unroll
        for (int s = 0; s < 2; ++s) {
            float4 f0 = *(const float4*)(xrow + (s << 5));
            float4 f1 = *(const float4*)(xrow + (s << 5) + 4);
            CVT8(f0, f1, xh[rt][s], xl[rt][s]);
        }
    }

    float m1[4], m2[4];
    int bi[4];
#pragma unroll
    for (int rt = 0; rt < 4; ++rt) { m1[rt] = -3e38f; m2[rt] = -3e38f; bi[rt] = 0; }

    bf16x8 a0, a1, a2, a3;  // eh slice0/1, el slice0/1
    f32x4 cb;
    LOADA(a0, a1, a2, a3, cb, k0);
    for (int tb = k0; tb < kend; tb += 16) {
        bf16x8 n0, n1, n2, n3;
        f32x4 nb;
        int tn = tb + 16 < kend ? tb + 16 : k0;
        LOADA(n0, n1, n2, n3, nb, tn);

        f32x4 acc[4];
#pragma unroll
        for (int rt = 0; rt < 4; ++rt)
            acc[rt] = __builtin_amdgcn_mfma_f32_16x16x32_bf16(a0, xh[rt][0], cb, 0, 0, 0);
#pragma unroll
        for (int rt = 0; rt < 4; ++rt)
            acc[rt] = __builtin_amdgcn_mfma_f32_16x16x32_bf16(a2, xh[rt][0], acc[rt], 0, 0, 0);
#pragma unroll
        for (int rt = 0; rt < 4; ++rt)
            acc[rt] = __builtin_amdgcn_mfma_f32_16x16x32_bf16(a0, xl[rt][0], acc[rt], 0, 0, 0);
#pragma unroll
        for (int rt = 0; rt < 4; ++rt)
            acc[rt] = __builtin_amdgcn_mfma_f32_16x16x32_bf16(a1, xh[rt][1], acc[rt], 0, 0, 0);
#pragma unroll
        for (int rt = 0; rt < 4; ++rt)
            acc[rt] = __builtin_amdgcn_mfma_f32_16x16x32_bf16(a3, xh[rt][1], acc[rt], 0, 0, 0);
#pragma unroll
        for (int rt = 0; rt < 4; ++rt)
            acc[rt] = __builtin_amdgcn_mfma_f32_16x16x32_bf16(a1, xl[rt][1], acc[rt], 0, 0, 0);

        // top-2 update; per-lane codes ascend -> np first-min
#pragma unroll
        for (int rt = 0; rt < 4; ++rt) {
            int cbase = tb + g4;
#pragma unroll
            for (int j = 0; j < 4; ++j) {
                float v = acc[rt][j];
                int c = cbase + j;
                bool tk = v > m1[rt];
                m2[rt] = fminf(fmaxf(v, m2[rt]), m1[rt]);  // med3(v,m2,m1)
                m1[rt] = tk ? v : m1[rt];
                bi[rt] = tk ? c : bi[rt];
            }
        }
        a0 = n0; a1 = n1; a2 = n2; a3 = n3; cb = nb;
    }

    // merge the 4 code-groups (lanes sub, sub+16, sub+32, sub+48)
#pragma unroll
    for (int rt = 0; rt < 4; ++rt) {
#pragma unroll
        for (int off = 16; off <= 32; off <<= 1) {
            float om1 = __shfl_xor(m1[rt], off);
            float om2 = __shfl_xor(m2[rt], off);
            int obi = __shfl_xor(bi[rt], off);
            bool take = (om1 > m1[rt]) || (om1 == m1[rt] && obi < bi[rt]);
            m2[rt] = fmaxf(fminf(om1, m1[rt]), fmaxf(om2, m2[rt]));
            m1[rt] = take ? om1 : m1[rt];
            bi[rt] = take ? obi : bi[rt];
        }
    }

    // emit triples (lanes 0-15 own rows sub + 16*rt)
    if (lane < 16) {
#pragma unroll
        for (int rt = 0; rt < 4; ++rt) {
            int row = row0 + (rt << 4) + lane;
            float* tp = outq + (size_t)row * D + kslice * 3;
            tp[0] = m1[rt];
            tp[1] = m2[rt];
            tp[2] = __int_as_float(bi[rt]);
        }
    }
}

// merge k-slices, margin test, idx/counts/quantized/loss
__global__ __launch_bounds__(256) void vq_merge(
    const float* __restrict__ x, const float* __restrict__ emb,
    const float* __restrict__ eenp, int N, int K,
    float* __restrict__ outq, float* __restrict__ outidx,
    unsigned* __restrict__ counts, double* __restrict__ loss,
    unsigned* __restrict__ nunc, unsigned* __restrict__ list, unsigned cap) {
    const int rows0 = blockIdx.x * 256;
    const int r = rows0 + threadIdx.x;
    __shared__ int sdec[256];

    const float* tp = outq + (size_t)r * D;
    float4 t0 = *(const float4*)tp;          // m1a, m2a, bia, m1b
    float m2b = tp[4];
    int bb = __float_as_int(tp[5]);
    float m1 = t0.x, m2 = t0.y;
    int bi = __float_as_int(t0.z);
    float m1b = t0.w;
    // slice1 has higher codes: take only if strictly greater (np first-min)
    bool take = m1b > m1;
    m2 = fmaxf(fminf(m1, m1b), fmaxf(m2, m2b));
    m1 = take ? m1b : m1;
    bi = take ? bb : bi;

    int dec = bi;
    if (2.0f * (m1 - m2) < MARGIN) {
        unsigned pos = atomicAdd(nunc, 1u);
        if (pos < cap) {
            list[pos] = (unsigned)r;
            dec = -1;
        } else {
            dec = np_exact_argmin(x + (size_t)r * D, emb, eenp, K);
        }
    }
    if (dec >= 0) {
        outidx[r] = (float)dec;
        atomicAdd(counts + dec, 1u);
    }
    sdec[threadIdx.x] = dec;
    __syncthreads();

    // quantized + loss: 4 lanes per row, 4 passes of 64 rows
    const int l = threadIdx.x >> 2;
    const int q = threadIdx.x & 3;
    double lpart = 0.0;
#pragma unroll
    for (int p = 0; p < 4; ++p) {
        int dp = sdec[p * 64 + l];
        if (dp >= 0) {
            int row = rows0 + p * 64 + l;
            int qo = q << 4;
            const float4* ep = (const float4*)(emb + (size_t)dp * D + qo);
            const float4* xp = (const float4*)(x + (size_t)row * D + qo);
            float4* qp = (float4*)(outq + (size_t)row * D + qo);
#pragma unroll
            for (int j = 0; j < 4; ++j) {
                float4 ev = ep[j], xv = xp[j];
                qp[j] = ev;
                double d0 = (double)ev.x - (double)xv.x;
                double d1 = (double)ev.y - (double)xv.y;
                double d2 = (double)ev.z - (double)xv.z;
                double d3 = (double)ev.w - (double)xv.w;
                lpart += d0 * d0 + d1 * d1 + d2 * d2 + d3 * d3;
            }
        }
    }
#pragma unroll
    for (int off = 32; off; off >>= 1) lpart += __shfl_down(lpart, off);
    __shared__ double ls[4];
    if ((threadIdx.x & 63) == 0) ls[threadIdx.x >> 6] = lpart;
    __syncthreads();
    if (threadIdx.x == 0) atomicAdd(loss, ls[0] + ls[1] + ls[2] + ls[3]);
}

// wave-per-4-rows exact np-f32 argmin; eT stream shared across the batch
__global__ __launch_bounds__(64) void vq_fallback(
    const float* __restrict__ x, const float* __restrict__ emb,
    const float* __restrict__ eT, const float* __restrict__ eenp, int N, int K,
    float* __restrict__ outq, float* __restrict__ outidx,
    unsigned* __restrict__ counts, double* __restrict__ loss,
    const unsigned* __restrict__ nunc, const unsigned* __restrict__ list,
    unsigned cap) {
    unsigned n = *nunc;
    if (n > cap) n = cap;
    int lane = threadIdx.x;
    const f32x4* eT4 = (const f32x4*)eT;  // [D][K/4]
    __shared__ float sx[4][64];
    for (unsigned base = blockIdx.x * 4; base < n; base += gridDim.x * 4) {
        int nb = (int)(n - base < 4u ? n - base : 4u);
#pragma unroll
        for (int j = 0; j < 4; ++j)
            if (j < nb) sx[j][lane] = x[(size_t)list[base + j] * D + lane];
        float xx[4];
#pragma unroll
        for (int j = 0; j < 4; ++j)
            if (j < nb) xx[j] = np_pairwise_sumsq64(sx[j]);  // np-exact, LDS bcast

        f32x4 dt[4][4];
#pragma unroll
        for (int j = 0; j < 4; ++j)
#pragma unroll
            for (int kk = 0; kk < 4; ++kk) dt[j][kk] = (f32x4){0.f, 0.f, 0.f, 0.f};

#pragma unroll 4
        for (int d = 0; d < D; ++d) {
            f32x4 ev[4];
#pragma unroll
            for (int kk = 0; kk < 4; ++kk)
                ev[kk] = eT4[(size_t)d * 256 + kk * 64 + lane];
#pragma unroll
            for (int j = 0; j < 4; ++j) {
                if (j < nb) {
                    float xv = sx[j][d];
#pragma unroll
                    for (int kk = 0; kk < 4; ++kk) {
                        dt[j][kk][0] = __fmaf_rn(xv, ev[kk][0], dt[j][kk][0]);
                        dt[j][kk][1] = __fmaf_rn(xv, ev[kk][1], dt[j][kk][1]);
                        dt[j][kk][2] = __fmaf_rn(xv, ev[kk][2], dt[j][kk][2]);
                        dt[j][kk][3] = __fmaf_rn(xv, ev[kk][3], dt[j][kk][3]);
                    }
                }
            }
        }

#pragma unroll
        for (int j = 0; j < 4; ++j) {
            if (j < nb) {
                float bm = 1e30f;
                int bi = 0;
#pragma unroll
                for (int kk = 0; kk < 4; ++kk)
#pragma unroll
                    for (int jj = 0; jj < 4; ++jj) {
                        int k = kk * 256 + lane * 4 + jj;  // ascending in lane
                        float dist = __fsub_rn(__fadd_rn(xx[j], eenp[k]),
                                               __fmul_rn(2.0f, dt[j][kk][jj]));
                        if (dist < bm) { bm = dist; bi = k; }
                    }
                // wave argmin, ties -> lowest index (numpy first-occurrence)
#pragma unroll
                for (int off = 1; off < 64; off <<= 1) {
                    float ov = __shfl_xor(bm, off);
                    int oi = __shfl_xor(bi, off);
                    if (ov < bm || (ov == bm && oi < bi)) { bm = ov; bi = oi; }
                }
                int r = (int)list[base + j];
                float ev = emb[(size_t)bi * D + lane];
                float xv = sx[j][lane];
                outq[(size_t)r * D + lane] = ev;
                double df = (double)ev - (double)xv;
                double lp = df * df;
#pragma unroll
                for (int off = 32; off; off >>= 1) lp += __shfl_down(lp, off);
                if (lane == 0) {
                    outidx[r] = (float)bi;
                    atomicAdd(counts + bi, 1u);
                    atomicAdd(loss, lp);
                }
            }
        }
    }
}

__global__ __launch_bounds__(256) void vq_final(
    const unsigned* __restrict__ counts, const double* __restrict__ loss,
    int N, int K, float* __restrict__ out_loss, float* __restrict__ out_perp) {
    double part = 0.0;
    for (int k = threadIdx.x; k < K; k += 256) {
        double p = (double)counts[k] / (double)N;
        part += p * log(p + 1e-10);
    }
#pragma unroll
    for (int off = 32; off; off >>= 1) part += __shfl_down(part, off);
    __shared__ double ls[4];
    if ((threadIdx.x & 63) == 0) ls[threadIdx.x >> 6] = part;
    __syncthreads();
    if (threadIdx.x == 0) {
        double s = ls[0] + ls[1] + ls[2] + ls[3];
        *out_perp = (float)exp(-s);
        double diff2 = *loss / ((double)N * (double)D);
        *out_loss = (float)(1.25 * diff2);
    }
}

extern "C" void kernel_launch(void* const* d_in, const int* in_sizes, int n_in,
                              void* d_out, int out_size, void* d_ws, size_t ws_size,
                              hipStream_t stream) {
    const float* x = (const float*)d_in[0];
    const float* emb = (const float*)d_in[1];
    int N = in_sizes[0] / D;
    int K = in_sizes[1] / D;

    float* outq = (float*)d_out;
    float* out_loss = outq + (size_t)N * D;
    float* outidx = out_loss + 1;
    float* out_perp = outidx + N;

    char* ws = (char*)d_ws;
    unsigned* counts = (unsigned*)ws;                          // K*4
    unsigned* nunc = (unsigned*)(ws + (size_t)K * 4);          // 4 (+4 pad)
    double* loss = (double*)(ws + (size_t)K * 4 + 8);          // 8
    float* neh = (float*)(ws + (size_t)K * 4 + 16);            // K*4
    float* eenp = (float*)(ws + (size_t)K * 8 + 16);           // K*4
    unsigned short* eh = (unsigned short*)(ws + (size_t)K * 12 + 16);  // K*D*2
    unsigned short* el = (unsigned short*)(ws + (size_t)K * 12 + 16 + (size_t)K * D * 2);
    float* eT = (float*)(ws + (size_t)K * 12 + 16 + (size_t)K * D * 4);  // D*K*4
    size_t head = (size_t)K * 12 + 16 + (size_t)K * D * 8;
    unsigned* list = (unsigned*)(ws + head);
    unsigned cap = 0;
    if (ws_size > head + 4) cap = (unsigned)((ws_size - head) / 4);
    if (cap > (unsigned)N) cap = (unsigned)N;

    hipMemsetAsync(d_ws, 0, (size_t)K * 4 + 16, stream);  // counts+nunc+loss

    int nb_ehel = (K * D / 8 + 255) / 256;
    int nb_sum = (K + 255) / 256;
    int nb_eT = (K * D + 255) / 256;
    vq_prep_all<<<nb_ehel + nb_sum + nb_eT, 256, 0, stream>>>(
        emb, K, eenp, neh, eh, el, eT);
    vq_screen<<<(N / 256) * KS, 256, 0, stream>>>(x, eh, el, neh, N, K, outq);
    vq_merge<<<N / 256, 256, 0, stream>>>(x, emb, eenp, N, K, outq, outidx,
                                          counts, loss, nunc, list, cap);
    vq_fallback<<<1024, 64, 0, stream>>>(x, emb, eT, eenp, N, K, outq, outidx,
                                         counts, loss, nunc, list, cap);
    vq_final<<<1, 256, 0, stream>>>(counts, loss, N, K, out_loss, out_perp);
}